// Round 2
// baseline (458.450 us; speedup 1.0000x reference)
//
#include <hip/hip_runtime.h>
#include <stdint.h>

// Problem constants (fixed by reference setup_inputs)
#define BB 8192
#define DD 4096
#define HH 2048
#define DW (DD / 32)   // 128 words per x / Wrow row
#define HW (HH / 32)   // 64 words per hb / Wcol row

// ---------------------------------------------------------------------------
// Pack rows of a [R][4096] float matrix into bits (bit = v >= thresh).
// One thread per element; wave of 64 lanes covers 64 consecutive d for the
// same row -> __ballot gives 64 bits, lane 0 writes two uint32 words.
// ---------------------------------------------------------------------------
__global__ void k_pack_bits(const float* __restrict__ src,
                            uint32_t* __restrict__ dst, float thresh) {
    int flat = blockIdx.x * blockDim.x + threadIdx.x;   // over R*DD
    int row = flat >> 12;          // / 4096
    int d   = flat & (DD - 1);
    bool bit = src[flat] >= thresh;
    unsigned long long m = __ballot(bit);
    if ((threadIdx.x & 63) == 0) {
        int wd = d >> 5;           // even (d % 64 == 0 here)
        dst[row * DW + wd]     = (uint32_t)m;
        dst[row * DW + wd + 1] = (uint32_t)(m >> 32);
    }
}

// ---------------------------------------------------------------------------
// Build the bit-transposed weight: Wcol[d][jw] bit i = Wb[jw*32+i][d].
// Lanes share the source word (d>>5 constant over 32 lanes) -> L1 broadcast.
// ---------------------------------------------------------------------------
__global__ void k_wcol(const uint32_t* __restrict__ Wrow,
                       uint32_t* __restrict__ Wcol) {
    int flat = blockIdx.x * blockDim.x + threadIdx.x;   // over HW*DD = 262144
    int jw = flat >> 12;           // 0..63
    int d  = flat & (DD - 1);
    int dw = d >> 5, db = d & 31;
    uint32_t w = 0;
#pragma unroll
    for (int i = 0; i < 32; ++i) {
        w |= ((Wrow[(jw * 32 + i) * DW + dw] >> db) & 1u) << i;
    }
    Wcol[d * HW + jw] = w;
}

// ---------------------------------------------------------------------------
// Integer thresholds: smallest integer c with (float)c + bias >= 1.0f,
// matching the reference's fp32 compare exactly (counts are small ints,
// exactly representable in fp32).
// ---------------------------------------------------------------------------
__device__ __forceinline__ int calc_thresh(float bias) {
    float need = 1.0f - bias;
    if (!(need == need)) return 2000000000;       // NaN bias: never fires
    if (need > 1.0e9f)  return 2000000000;        // never fires
    if (need < -1.0e9f) return -2000000000;       // always fires
    int t = (int)ceilf(need);
    // adjust to exact fp32 semantics at the boundary
#pragma unroll
    for (int it = 0; it < 2; ++it)
        if ((float)(t - 1) + bias >= 1.0f) t--;
#pragma unroll
    for (int it = 0; it < 2; ++it)
        if ((float)t + bias < 1.0f) t++;
    return t;
}

__global__ void k_thresh(const float* __restrict__ b_enc,
                         const float* __restrict__ b0,
                         const float* __restrict__ b3,
                         int* __restrict__ t1, int* __restrict__ t2) {
    int tid = blockIdx.x * blockDim.x + threadIdx.x;  // HH + DD threads
    if (tid < HH) {
        t1[tid] = calc_thresh(b_enc[tid] + b0[tid]);
    } else {
        int d = tid - HH;
        t2[d] = calc_thresh(b3[d]);
    }
}

// ---------------------------------------------------------------------------
// GEMM1: h[b][j] = (popcount(xb[b] & Wrow[j]) reaches t1[j]).
// Early exit is exact (count is monotone). Wave = 64 consecutive j, same b:
// xb words broadcast across lanes; ballot-pack the h bits.
// ---------------------------------------------------------------------------
__global__ void k_gemm1(const uint32_t* __restrict__ xb,
                        const uint32_t* __restrict__ Wrow,
                        const int* __restrict__ t1,
                        uint32_t* __restrict__ hb) {
    int flat = blockIdx.x * blockDim.x + threadIdx.x;   // over BB*HH
    int b = flat >> 11;            // / 2048
    int j = flat & (HH - 1);
    const uint4* xr = (const uint4*)(xb + (size_t)b * DW);
    const uint4* wr = (const uint4*)(Wrow + (size_t)j * DW);
    int t = t1[j];
    int c = 0;
    if (t > 0) {
        for (int k = 0; k < DW / 4; ++k) {   // 32 iters of 128 bits
            uint4 a = xr[k];
            uint4 w = wr[k];
            c += __popc(a.x & w.x) + __popc(a.y & w.y) +
                 __popc(a.z & w.z) + __popc(a.w & w.w);
            if (c >= t) break;
        }
    }
    unsigned long long m = __ballot(c >= t);
    if ((threadIdx.x & 63) == 0) {
        int jw = j >> 5;           // even
        hb[(size_t)b * HW + jw]     = (uint32_t)m;
        hb[(size_t)b * HW + jw + 1] = (uint32_t)(m >> 32);
    }
}

// ---------------------------------------------------------------------------
// GEMM2: out[b][d] = (popcount(hb[b] & Wcol[d]) reaches t2[d]) as 0/1 float.
// h is statistically near-all-ones and Wcol ~50% dense -> exits on word 0
// almost always. Coalesced float writes.
// ---------------------------------------------------------------------------
__global__ void k_gemm2(const uint32_t* __restrict__ hb,
                        const uint32_t* __restrict__ Wcol,
                        const int* __restrict__ t2,
                        float* __restrict__ out) {
    int flat = blockIdx.x * blockDim.x + threadIdx.x;   // over BB*DD
    int b = flat >> 12;            // / 4096
    int d = flat & (DD - 1);
    const uint4* hr = (const uint4*)(hb + (size_t)b * HW);
    const uint4* wc = (const uint4*)(Wcol + (size_t)d * HW);
    int t = t2[d];
    int c = 0;
    if (t > 0) {
        for (int k = 0; k < HW / 4; ++k) {   // 16 iters of 128 bits
            uint4 a = hr[k];
            uint4 w = wc[k];
            c += __popc(a.x & w.x) + __popc(a.y & w.y) +
                 __popc(a.z & w.z) + __popc(a.w & w.w);
            if (c >= t) break;
        }
    }
    out[flat] = (c >= t) ? 1.0f : 0.0f;
}

// ---------------------------------------------------------------------------
extern "C" void kernel_launch(void* const* d_in, const int* in_sizes, int n_in,
                              void* d_out, int out_size, void* d_ws, size_t ws_size,
                              hipStream_t stream) {
    const float* x     = (const float*)d_in[0];   // [B, D]
    const float* W     = (const float*)d_in[1];   // [H, D]
    const float* b_enc = (const float*)d_in[2];   // [H]
    const float* b0    = (const float*)d_in[3];   // [H]
    const float* b3    = (const float*)d_in[4];   // [D]
    float* out = (float*)d_out;                   // [B, D]

    // Workspace layout (all 16B-aligned offsets)
    char* ws = (char*)d_ws;
    uint32_t* Wrow = (uint32_t*)(ws);                         // 1 MB
    uint32_t* Wcol = (uint32_t*)(ws + (1u << 20));            // 1 MB
    uint32_t* xb   = (uint32_t*)(ws + (2u << 20));            // 4 MB
    uint32_t* hb   = (uint32_t*)(ws + (6u << 20));            // 2 MB
    int*      t1   = (int*)(ws + (8u << 20));                 // 8 KB
    int*      t2   = (int*)(ws + (8u << 20) + 8192);          // 16 KB

    const int BLK = 256;

    // 1. pack W rows (bit = W >= 0.5)
    k_pack_bits<<<(HH * DD) / BLK, BLK, 0, stream>>>(W, Wrow, 0.5f);
    // 2. pack x rows (x is exactly 0.0/1.0)
    k_pack_bits<<<(BB * DD) / BLK, BLK, 0, stream>>>(x, xb, 0.5f);
    // 3. bit-transpose W
    k_wcol<<<(HW * DD) / BLK, BLK, 0, stream>>>(Wrow, Wcol);
    // 4. thresholds
    k_thresh<<<(HH + DD) / BLK, BLK, 0, stream>>>(b_enc, b0, b3, t1, t2);
    // 5. encoder GEMM + binarize + pack
    k_gemm1<<<(BB * HH) / BLK, BLK, 0, stream>>>(xb, Wrow, t1, hb);
    // 6. decoder GEMM + binarize
    k_gemm2<<<(BB * DD) / BLK, BLK, 0, stream>>>(hb, Wcol, t2, out);
}

// Round 3
// 324.674 us; speedup vs baseline: 1.4120x; 1.4120x over previous
//
#include <hip/hip_runtime.h>
#include <stdint.h>

// Problem constants (fixed by reference setup_inputs)
#define BB 8192
#define DD 4096
#define HH 2048
#define DW (DD / 32)   // 128 words per x / Wb row
#define HW (HH / 32)   // 64 words per h row / Wcol column

// ---------------------------------------------------------------------------
// pack_x: one thread per 32-bit WORD. Thread reads 128B contiguous floats,
// builds one word. Wave covers 8KB contiguous input; word writes coalesced.
// flat over BB*DW: b = flat>>7, wd = flat&127.
// ---------------------------------------------------------------------------
__global__ void k_pack_x(const float* __restrict__ x,
                         uint32_t* __restrict__ xb) {
    int flat = blockIdx.x * blockDim.x + threadIdx.x;
    int b  = flat >> 7;
    int wd = flat & (DW - 1);
    const float4* p = (const float4*)(x + (size_t)b * DD + 32 * wd);
    uint32_t w = 0;
#pragma unroll
    for (int q = 0; q < 8; ++q) {
        float4 v = p[q];
        w |= (v.x >= 0.5f ? 1u : 0u) << (4 * q + 0);
        w |= (v.y >= 0.5f ? 1u : 0u) << (4 * q + 1);
        w |= (v.z >= 0.5f ? 1u : 0u) << (4 * q + 2);
        w |= (v.w >= 0.5f ? 1u : 0u) << (4 * q + 3);
    }
    xb[flat] = w;
}

// ---------------------------------------------------------------------------
// pack_W_rows -> WrowT4: layout [k4 0..31][j 0..2047] of uint4 = words
// {4k4..4k4+3} of binarized W row j. Consecutive j are contiguous so gemm1's
// per-lane uint4 load is coalesced across the wave.
// Thread per (j,k) word: j = flat>>7, k = flat&127. Reads 128B contiguous.
// ---------------------------------------------------------------------------
__global__ void k_pack_wrow(const float* __restrict__ W,
                            uint32_t* __restrict__ WrowT4) {
    int flat = blockIdx.x * blockDim.x + threadIdx.x;   // over HH*DW = 262144
    int j = flat >> 7;
    int k = flat & (DW - 1);
    const float4* p = (const float4*)(W + (size_t)j * DD + 32 * k);
    uint32_t w = 0;
#pragma unroll
    for (int q = 0; q < 8; ++q) {
        float4 v = p[q];
        w |= (v.x >= 0.5f ? 1u : 0u) << (4 * q + 0);
        w |= (v.y >= 0.5f ? 1u : 0u) << (4 * q + 1);
        w |= (v.z >= 0.5f ? 1u : 0u) << (4 * q + 2);
        w |= (v.w >= 0.5f ? 1u : 0u) << (4 * q + 3);
    }
    // uint4 element (k>>2, j), component k&3
    WrowT4[((size_t)(k >> 2) * HH + j) * 4 + (k & 3)] = w;
}

// ---------------------------------------------------------------------------
// pack_W_cols -> WcolT: word-plane layout [kw 0..63][d 0..4095], uint32.
// WcolT[kw][d] bit i = (W[(kw*32+i)][d] >= 0.5). Plane 0 (16KB) stays L1-
// resident for gemm2. Lanes take consecutive d -> every read/write coalesced.
// ---------------------------------------------------------------------------
__global__ void k_pack_wcol(const float* __restrict__ W,
                            uint32_t* __restrict__ WcolT) {
    int flat = blockIdx.x * blockDim.x + threadIdx.x;   // over HW*DD = 262144
    int kw = flat >> 12;
    int d  = flat & (DD - 1);
    uint32_t w = 0;
#pragma unroll
    for (int i = 0; i < 32; ++i) {
        float v = W[(size_t)(kw * 32 + i) * DD + d];
        w |= (v >= 0.5f ? 1u : 0u) << i;
    }
    WcolT[(size_t)kw * DD + d] = w;
}

// ---------------------------------------------------------------------------
// Integer thresholds: smallest integer c with (float)c + bias >= 1.0f.
// Counts <= 4096 are exact in fp32 so the integer compare is exact.
// ---------------------------------------------------------------------------
__device__ __forceinline__ int calc_thresh(float bias) {
    float need = 1.0f - bias;
    if (!(need == need)) return 2000000000;       // NaN bias: never fires
    if (need > 1.0e9f)  return 2000000000;
    if (need < -1.0e9f) return -2000000000;
    int t = (int)ceilf(need);
#pragma unroll
    for (int it = 0; it < 2; ++it)
        if ((float)(t - 1) + bias >= 1.0f) t--;
#pragma unroll
    for (int it = 0; it < 2; ++it)
        if ((float)t + bias < 1.0f) t++;
    return t;
}

__global__ void k_thresh(const float* __restrict__ b_enc,
                         const float* __restrict__ b0,
                         const float* __restrict__ b3,
                         int* __restrict__ t1, int* __restrict__ t2) {
    int tid = blockIdx.x * blockDim.x + threadIdx.x;  // HH + DD threads
    if (tid < HH) {
        t1[tid] = calc_thresh(b_enc[tid] + b0[tid]);
    } else {
        int d = tid - HH;
        t2[d] = calc_thresh(b3[d]);
    }
}

// ---------------------------------------------------------------------------
// GEMM1: h[b][j] = popcount(x_row & W_row_j) >= t1[j]. One thread per (b,j);
// wave = 64 consecutive j, same b. Per iter: uint4 of 4 k-words per lane
// (coalesced 16B/lane from WrowT4), x words broadcast. Early exit exact
// (count monotone). h bits ballot-packed.
// ---------------------------------------------------------------------------
__global__ void k_gemm1(const uint32_t* __restrict__ xb,
                        const uint4* __restrict__ WrowT4,
                        const int* __restrict__ t1,
                        uint32_t* __restrict__ hb) {
    int flat = blockIdx.x * blockDim.x + threadIdx.x;   // over BB*HH
    int b = flat >> 11;
    int j = flat & (HH - 1);
    const uint32_t* xr = xb + (size_t)b * DW;
    int t = t1[j];
    int c = 0;
    if (t > 0) {
        for (int k4 = 0; k4 < DW / 4; ++k4) {     // 32 iters max
            uint4 w = WrowT4[(size_t)k4 * HH + j];          // coalesced
            uint4 a = *(const uint4*)(xr + 4 * k4);         // broadcast
            c += __popc(a.x & w.x) + __popc(a.y & w.y) +
                 __popc(a.z & w.z) + __popc(a.w & w.w);
            if (c >= t) break;
        }
    }
    unsigned long long m = __ballot(c >= t);
    if ((threadIdx.x & 63) == 0) {
        int jw = j >> 5;           // even
        hb[(size_t)b * HW + jw]     = (uint32_t)m;
        hb[(size_t)b * HW + jw + 1] = (uint32_t)(m >> 32);
    }
}

// ---------------------------------------------------------------------------
// GEMM2: out[b][d] = popcount(h_row & W_col_d) >= t2[d]. One thread per 4
// outputs: per iter one uint4 load of word kw for d0..d0+3 (coalesced, plane
// 0 is 16KB -> L1-resident), h word broadcast. Typically exits on kw=0.
// float4 coalesced stores.
// ---------------------------------------------------------------------------
__global__ void k_gemm2(const uint32_t* __restrict__ hb,
                        const uint32_t* __restrict__ WcolT,
                        const int* __restrict__ t2,
                        float* __restrict__ out) {
    int flat = blockIdx.x * blockDim.x + threadIdx.x;   // over BB*DD/4
    int b  = flat >> 10;
    int d0 = (flat & 1023) * 4;
    const uint32_t* hr = hb + (size_t)b * HW;
    int4 tt = *(const int4*)(t2 + d0);
    int c0 = 0, c1 = 0, c2 = 0, c3 = 0;
    for (int kw = 0; kw < HW; ++kw) {
        if (c0 >= tt.x && c1 >= tt.y && c2 >= tt.z && c3 >= tt.w) break;
        uint32_t hw = hr[kw];                               // broadcast
        uint4 w = *(const uint4*)(WcolT + (size_t)kw * DD + d0); // coalesced
        c0 += __popc(hw & w.x);
        c1 += __popc(hw & w.y);
        c2 += __popc(hw & w.z);
        c3 += __popc(hw & w.w);
    }
    float4 r;
    r.x = (c0 >= tt.x) ? 1.0f : 0.0f;
    r.y = (c1 >= tt.y) ? 1.0f : 0.0f;
    r.z = (c2 >= tt.z) ? 1.0f : 0.0f;
    r.w = (c3 >= tt.w) ? 1.0f : 0.0f;
    *(float4*)(out + (size_t)b * DD + d0) = r;
}

// ---------------------------------------------------------------------------
extern "C" void kernel_launch(void* const* d_in, const int* in_sizes, int n_in,
                              void* d_out, int out_size, void* d_ws, size_t ws_size,
                              hipStream_t stream) {
    const float* x     = (const float*)d_in[0];   // [B, D]
    const float* W     = (const float*)d_in[1];   // [H, D]
    const float* b_enc = (const float*)d_in[2];   // [H]
    const float* b0    = (const float*)d_in[3];   // [H]
    const float* b3    = (const float*)d_in[4];   // [D]
    float* out = (float*)d_out;                   // [B, D]

    // Workspace layout (16B-aligned offsets)
    char* ws = (char*)d_ws;
    uint32_t* WrowT4 = (uint32_t*)(ws);                       // 1 MB
    uint32_t* WcolT  = (uint32_t*)(ws + (1u << 20));          // 1 MB
    uint32_t* xb     = (uint32_t*)(ws + (2u << 20));          // 4 MB
    uint32_t* hb     = (uint32_t*)(ws + (6u << 20));          // 2 MB
    int*      t1     = (int*)(ws + (8u << 20));               // 8 KB
    int*      t2     = (int*)(ws + (8u << 20) + 8192);        // 16 KB

    const int BLK = 256;

    k_pack_wrow<<<(HH * DW) / BLK, BLK, 0, stream>>>(W, WrowT4);
    k_pack_wcol<<<(HW * DD) / BLK, BLK, 0, stream>>>(W, WcolT);
    k_pack_x  <<<(BB * DW) / BLK, BLK, 0, stream>>>(x, xb);
    k_thresh  <<<(HH + DD) / BLK, BLK, 0, stream>>>(b_enc, b0, b3, t1, t2);
    k_gemm1   <<<(BB * HH) / BLK, BLK, 0, stream>>>(xb, (const uint4*)WrowT4, t1, hb);
    k_gemm2   <<<(BB * DD / 4) / BLK, BLK, 0, stream>>>(hb, WcolT, t2, out);
}